// Round 5
// baseline (289.524 us; speedup 1.0000x reference)
//
#include <hip/hip_runtime.h>
#include <math.h>

#define BATCH 128
#define NANCH 8400
#define NMSK  300
#define KPT   17
#define OUTC  56   // 4 box + 1 score + 34 kpt + 17 vis
#define CAND  768  // candidate slots (>=300 + tie margin)
#define NTHR  1024
#define NWAVE 16

__device__ __forceinline__ void prior_of(int i, float& stride, float& cx, float& cy) {
    int row, col;
    if (i < 6400)      { stride = 8.0f;  row = i / 80;              col = i - row * 80; }
    else if (i < 8000) { int ii = i - 6400; stride = 16.0f; row = ii / 40; col = ii - row * 40; }
    else               { int ii = i - 8000; stride = 32.0f; row = ii / 20; col = ii - row * 20; }
    cx = ((float)col + 0.5f) * stride;
    cy = ((float)row + 0.5f) * stride;
}

// partial barrier for waves 0..7 only (LDS counter; waves 8..15 never touch it)
__device__ __forceinline__ void half_barrier(unsigned int* cnt, unsigned int target) {
    __threadfence_block();
    if ((threadIdx.x & 63) == 0)
        __hip_atomic_fetch_add(cnt, 1u, __ATOMIC_ACQ_REL, __HIP_MEMORY_SCOPE_WORKGROUP);
    while (__hip_atomic_load(cnt, __ATOMIC_ACQUIRE, __HIP_MEMORY_SCOPE_WORKGROUP) < target)
        __builtin_amdgcn_s_sleep(1);
    __threadfence_block();
}

// ---------------------------------------------------------------------------
// K1: all B*N fused scores (np-f32-exact) -> sc bits.
// DO NOT change this math: bit-exact vs np reference (absmax 0.0, R2-R4).
// ---------------------------------------------------------------------------
__global__ __launch_bounds__(256) void scores_kernel(
    const float* __restrict__ cls, const float* __restrict__ obj,
    unsigned int* __restrict__ sc)
{
    int i = blockIdx.x * 256 + threadIdx.x;
    if (i < BATCH * NANCH) {
        float ea = (float)exp(-(double)cls[i]);   // correctly-rounded f32 exp == np.exp
        float eo = (float)exp(-(double)obj[i]);
        float sa = 1.0f / (1.0f + ea);
        float so = 1.0f / (1.0f + eo);
        sc[i] = __float_as_uint(sa * so);
    }
}

// ---------------------------------------------------------------------------
// K2: per-batch everything. 128 blocks x 1024 threads.
// ---------------------------------------------------------------------------
__global__ __launch_bounds__(NTHR) void fused_kernel(
    const float* __restrict__ cls, const float* __restrict__ obj,
    const unsigned int* __restrict__ sc_g, int has_sc,
    const float* __restrict__ bbox, const float* __restrict__ kofs,
    const float* __restrict__ kvis, float* __restrict__ out)
{
    const int b    = blockIdx.x;
    const int tid  = threadIdx.x;
    const int w    = tid >> 6;
    const int lane = tid & 63;

    __shared__ unsigned int sc[NANCH];           // 33.6 KB
    __shared__ unsigned int whist[NWAVE * 256];  // 16 KB, per-wave private
    __shared__ unsigned int sh_prefix, sh_k, sh_cnt, barcnt;
    __shared__ unsigned long long ckey[CAND];    // 6 KB
    __shared__ float bx1[NMSK], by1[NMSK], bx2[NMSK], by2[NMSK], area[NMSK], sval[NMSK];
    __shared__ int   sidx[NMSK];
    __shared__ unsigned long long supl[NMSK * 6];  // stride 6 (16B align)

    // ---- init + zero round-3 histograms ----
    if (tid == 0) { sh_prefix = 0u; sh_k = NMSK; sh_cnt = 0u; barcnt = 0u; }
    for (int i = tid; i < NWAVE * 256; i += NTHR) whist[i] = 0u;
    __syncthreads();

    // ---- stage score bits, fused with round-3 (top byte) histogram ----
    unsigned int* myh = &whist[w * 256];
    if (has_sc) {
        const unsigned int* s = sc_g + (size_t)b * NANCH;
        for (int i = tid; i < NANCH; i += NTHR) {
            unsigned int key = s[i];
            sc[i] = key;
            atomicAdd(&myh[key >> 24], 1u);
        }
    } else {
        const float* c = cls + (size_t)b * NANCH;
        const float* o = obj + (size_t)b * NANCH;
        for (int i = tid; i < NANCH; i += NTHR) {
            float ea = (float)exp(-(double)c[i]);
            float eo = (float)exp(-(double)o[i]);
            unsigned int key = __float_as_uint((1.0f / (1.0f + ea)) * (1.0f / (1.0f + eo)));
            sc[i] = key;
            atomicAdd(&myh[key >> 24], 1u);
        }
    }
    __syncthreads();

    // ---- radix-select exact 300th-largest f32 bit pattern ----
    for (int r = 3; r >= 0; --r) {
        if (r < 3) {
            // zero + accumulate this round's histogram (wave-private)
            for (int i = tid; i < NWAVE * 256; i += NTHR) whist[i] = 0u;
            __syncthreads();
            unsigned int pfx = sh_prefix;
            for (int i = tid; i < NANCH; i += NTHR) {
                unsigned int key = sc[i];
                if ((key >> ((r + 1) * 8)) == pfx)
                    atomicAdd(&myh[(key >> (r * 8)) & 0xFFu], 1u);
            }
            __syncthreads();
        }
        // wave0: reduce 16 regions, suffix-scan, pick digit — all in registers
        if (w == 0) {
            unsigned int b0 = 0, b1 = 0, b2 = 0, b3 = 0;
            #pragma unroll 4
            for (int ww = 0; ww < NWAVE; ++ww) {
                const unsigned int* hh = &whist[ww * 256 + 4 * lane];
                b0 += hh[0]; b1 += hh[1]; b2 += hh[2]; b3 += hh[3];
            }
            unsigned int tot = b0 + b1 + b2 + b3;
            unsigned int v = tot;
            #pragma unroll
            for (int d = 1; d < 64; d <<= 1) {
                unsigned int t2 = (unsigned int)__shfl_down((int)v, d, 64);
                if (lane + d < 64) v += t2;
            }
            unsigned int above = v - tot;          // sum over lanes > lane
            unsigned int s3 = above + b3;          // suf(4l+3)
            unsigned int s2 = s3 + b2;
            unsigned int s1 = s2 + b1;
            unsigned int s0 = s1 + b0;             // suf(4l+0)
            unsigned int snext = (unsigned int)__shfl_down((int)s0, 1, 64);
            if (lane == 63) snext = 0u;
            unsigned int kcur = sh_k;
            unsigned int pfx  = sh_prefix;
            unsigned int ge[4] = { s0, s1, s2, s3 };
            unsigned int gn[4] = { s1, s2, s3, snext };
            #pragma unroll
            for (int j = 0; j < 4; ++j) {
                if (ge[j] >= kcur && gn[j] < kcur) {   // exactly one lane/j
                    sh_prefix = (pfx << 8) | (unsigned int)(4 * lane + j);
                    sh_k      = kcur - gn[j];
                }
            }
        }
        __syncthreads();
    }

    // ---- compact all keys >= pivot (packed (bits<<32)|(~idx)) ----
    unsigned int pivot_bits = sh_prefix;
    for (int i = tid; i < NANCH; i += NTHR) {
        unsigned int key = sc[i];
        if (key >= pivot_bits) {
            unsigned int p = atomicAdd(&sh_cnt, 1u);
            if (p < CAND)
                ckey[p] = ((unsigned long long)key << 32)
                        | (unsigned long long)(0xFFFFFFFFu - (unsigned int)i);
        }
    }
    __syncthreads();
    unsigned int M = sh_cnt; if (M > CAND) M = CAND;

    // ---- rank order (score desc, idx asc == lax.top_k) ----
    if (tid < (int)M) {
        unsigned long long mine = ckey[tid];
        int rank = 0;
        for (unsigned int t2 = 0; t2 < M; ++t2) rank += (ckey[t2] > mine) ? 1 : 0;
        if (rank < NMSK) {
            sidx[rank] = (int)(0xFFFFFFFFu - (unsigned int)(mine & 0xFFFFFFFFull));
            sval[rank] = __uint_as_float((unsigned int)(mine >> 32));
        }
    }
    __syncthreads();   // sidx/sval ready; block splits from here (no more block syncs)

    float* ob = out + (size_t)b * NMSK * OUTC;

    if (w >= 8) {
        // ---- waves 8..15: gathered kpt decode + vis sigmoid (cols 5..55) ----
        const float* kof = kofs + (size_t)b * NANCH * 34;
        const float* kvi = kvis + (size_t)b * NANCH * KPT;
        for (int e = tid - 512; e < NMSK * 51; e += 512) {
            int j  = e / 51;
            int ci = e - j * 51;
            int i  = sidx[j];
            float stride, cx, cy;
            prior_of(i, stride, cx, cy);
            float v;
            if (ci < 34) {
                float off = kof[(size_t)i * 34 + ci];
                v = off * stride + ((ci & 1) ? cy : cx);
            } else {
                float x = kvi[(size_t)i * KPT + (ci - 34)];
                v = 1.0f / (1.0f + expf(-x));
            }
            ob[j * OUTC + 5 + ci] = v;
        }
        return;
    }

    // ---- waves 0..7: decode -> bitmask -> greedy, with partial barriers ----
    if (tid < NMSK) {
        int j = tid;
        int i = sidx[j];
        float stride, cx, cy;
        prior_of(i, stride, cx, cy);
        float4 bb = *(const float4*)(bbox + ((size_t)b * NANCH + (size_t)i) * 4);
        float x = bb.x * stride + cx;
        float y = bb.y * stride + cy;
        float ww = expf(bb.z) * stride;
        float hh = expf(bb.w) * stride;
        float x1 = x - 0.5f * ww, y1 = y - 0.5f * hh;
        float x2 = x + 0.5f * ww, y2 = y + 0.5f * hh;
        bx1[j] = x1; by1[j] = y1; bx2[j] = x2; by2[j] = y2;
        area[j] = fmaxf(x2 - x1, 0.0f) * fmaxf(y2 - y1, 0.0f);
        float4 bo; bo.x = x1; bo.y = y1; bo.z = x2; bo.w = y2;
        *(float4*)(ob + j * OUTC) = bo;          // cols 0..3 (224B stride: 16B aligned)
    }
    half_barrier(&barcnt, 8);

    // suppression bitmask: task = (row i, word w2), <=64 inner iters, 512 thr
    for (int t = tid; t < NMSK * 5; t += 512) {
        int w2 = t / NMSK;
        int i  = t - w2 * NMSK;
        int jlo = w2 * 64; if (jlo < i + 1) jlo = i + 1;
        int jhi = w2 * 64 + 64; if (jhi > NMSK) jhi = NMSK;
        unsigned long long m = 0;
        float ax1 = bx1[i], ay1 = by1[i], ax2 = bx2[i], ay2 = by2[i], aa = area[i];
        for (int j = jlo; j < jhi; ++j) {
            float lx = fmaxf(ax1, bx1[j]);
            float ly = fmaxf(ay1, by1[j]);
            float rx = fminf(ax2, bx2[j]);
            float ry = fminf(ay2, by2[j]);
            float iw = fmaxf(rx - lx, 0.0f);
            float ih = fmaxf(ry - ly, 0.0f);
            float inter = iw * ih;
            float iou = inter / (aa + area[i < j ? j : j] - inter + 1e-7f);
            if (iou > 0.65f) m |= 1ull << (j & 63);
        }
        supl[i * 6 + w2] = m;
    }
    half_barrier(&barcnt, 16);

    if (w == 0) {
        // register-replicated greedy scan (all 64 lanes redundant, uniform)
        unsigned long long k0 = ~0ull, k1 = ~0ull, k2 = ~0ull, k3 = ~0ull;
        unsigned long long k4 = (1ull << (NMSK - 256)) - 1ull;
        const unsigned long long* sp = supl;
        #define GSTEP(KW, I) \
            if (((KW) >> ((I) & 63)) & 1ull) { \
                const unsigned long long* s = sp + (size_t)(I) * 6; \
                k0 &= ~s[0]; k1 &= ~s[1]; k2 &= ~s[2]; k3 &= ~s[3]; k4 &= ~s[4]; }
        for (int i = 0;   i < 64;   ++i) { GSTEP(k0, i) }
        for (int i = 64;  i < 128;  ++i) { GSTEP(k1, i) }
        for (int i = 128; i < 192;  ++i) { GSTEP(k2, i) }
        for (int i = 192; i < 256;  ++i) { GSTEP(k3, i) }
        for (int i = 256; i < NMSK; ++i) { GSTEP(k4, i) }
        #undef GSTEP
        // col 4: keep-masked score; iteration index == word index (j>>6)
        #pragma unroll
        for (int it = 0; it < 5; ++it) {
            int j = lane + 64 * it;
            if (j < NMSK) {
                unsigned long long kw = (it == 0) ? k0 : (it == 1) ? k1
                                       : (it == 2) ? k2 : (it == 3) ? k3 : k4;
                bool kp = (kw >> lane) & 1ull;
                ob[j * OUTC + 4] = kp ? sval[j] : 0.0f;
            }
        }
    }
}

// ---------------------------------------------------------------------------
extern "C" void kernel_launch(void* const* d_in, const int* in_sizes, int n_in,
                              void* d_out, int out_size, void* d_ws, size_t ws_size,
                              hipStream_t stream) {
    const float* cls  = (const float*)d_in[0];  // [B,N,1]
    const float* bbox = (const float*)d_in[1];  // [B,N,4]
    const float* obj  = (const float*)d_in[2];  // [B,N]
    const float* kofs = (const float*)d_in[3];  // [B,N,17,2]
    const float* kvis = (const float*)d_in[4];  // [B,N,17]
    float* out = (float*)d_out;                 // [B,300,56]

    size_t need_sc = (size_t)BATCH * NANCH * sizeof(unsigned int);
    unsigned int* sc = (unsigned int*)d_ws;
    int has_sc = (ws_size >= need_sc) ? 1 : 0;

    if (has_sc) {
        int nblk = (BATCH * NANCH + 255) / 256;
        scores_kernel<<<nblk, 256, 0, stream>>>(cls, obj, sc);
    }
    fused_kernel<<<BATCH, NTHR, 0, stream>>>(cls, obj, sc, has_sc,
                                             bbox, kofs, kvis, out);
}